// Round 2
// 223.357 us; speedup vs baseline: 1.0559x; 1.0559x over previous
//
#include <hip/hip_runtime.h>
#include <cstdint>
#include <cstddef>

// ---------- types ----------
typedef __attribute__((ext_vector_type(8))) __bf16 bf16x8;   // MFMA A/B frag (4 VGPRs)
typedef __attribute__((ext_vector_type(4))) float  f32x4;    // MFMA C/D frag

// s_waitcnt simm16 (gfx9/CDNA): [3:0] vmcnt lo, [6:4] expcnt, [11:8] lgkmcnt, [15:14] vmcnt hi
#define WAITCNT_VM(n) ((n & 0xF) | 0x70 | 0xF00 | (((n) >> 4) << 14))   // wait vmcnt<=n only
#define WAITCNT_LGKM0 (0xF | 0x70 | (3 << 14))                          // wait lgkmcnt==0 only

__device__ __forceinline__ unsigned short f32_to_bf16(float f) {
    union { float f; unsigned int u; } cv;
    cv.f = f;
    unsigned int u = cv.u;
    return (unsigned short)((u + 0x7fffu + ((u >> 16) & 1u)) >> 16);  // RNE
}

__device__ __forceinline__ float bf16_to_f32(unsigned short h) {
    union { unsigned int u; float f; } cv;
    cv.u = ((unsigned int)h) << 16;
    return cv.f;
}

// async global->LDS, 16 bytes per lane. LDS dest is wave-uniform base + lane*16.
__device__ __forceinline__ void async_copy16(const unsigned short* g, unsigned short* lds) {
    __builtin_amdgcn_global_load_lds(
        (const __attribute__((address_space(1))) unsigned int*)g,
        (__attribute__((address_space(3))) unsigned int*)lds,
        16, 0, 0);
}

// ---------- fused fp32 -> bf16 cast for all five inputs + lsum zeroing (R7) ----------
__global__ __launch_bounds__(256) void cast_all(
    const float* __restrict__ x,  const float* __restrict__ y,
    const float* __restrict__ wq, const float* __restrict__ wk, const float* __restrict__ wv,
    unsigned short* __restrict__ xb,  unsigned short* __restrict__ yb,
    unsigned short* __restrict__ wqb, unsigned short* __restrict__ wkb,
    unsigned short* __restrict__ wvb, float* __restrict__ lsum)
{
    int b = blockIdx.x;
    if (b >= 11264) {   // last block: zero lsum[4096]
        float4 z = {0.f, 0.f, 0.f, 0.f};
#pragma unroll
        for (int t = 0; t < 4; ++t)
            ((float4*)lsum)[threadIdx.x * 4 + t] = z;
        return;
    }
    const float* s; unsigned short* d; int base;
    if      (b < 4096)  { s = x;  d = xb;  base = b; }
    else if (b < 8192)  { s = y;  d = yb;  base = b - 4096; }
    else if (b < 9216)  { s = wq; d = wqb; base = b - 8192; }
    else if (b < 10240) { s = wk; d = wkb; base = b - 9216; }
    else                { s = wv; d = wvb; base = b - 10240; }
    int i = base * 256 + threadIdx.x;
    float4 v = ((const float4*)s)[i];
    ushort4 o;
    o.x = f32_to_bf16(v.x);
    o.y = f32_to_bf16(v.y);
    o.z = f32_to_bf16(v.z);
    o.w = f32_to_bf16(v.w);
    ((ushort4*)d)[i] = o;
}

// ---------- 1-deep prefetch GEMM core, BK=32 (R4/R7 proven; used by proj only) ----------
__device__ __forceinline__ void gemm_core_pf(
    const unsigned short* __restrict__ A, const unsigned short* __restrict__ B,
    int K, int rowBase, int colBase, int kBeg, int kEnd,
    unsigned short* ldsA, unsigned short* ldsB, f32x4 acc[4][4])
{
    const int tid  = threadIdx.x;
    const int lane = tid & 63;
    const int wave = tid >> 6;
    const int quad = lane >> 4;
    const int r    = lane & 15;
    const int wm   = wave >> 1;
    const int wn   = wave & 1;

    const int c1 = tid + 256;
    const long aOff0 = (long)(rowBase + (tid >> 2)) * K + (tid & 3) * 8;
    const long aOff1 = (long)(rowBase + (c1  >> 2)) * K + (c1  & 3) * 8;
    const long bOff0 = (long)(colBase + (tid >> 2)) * K + (tid & 3) * 8;
    const long bOff1 = (long)(colBase + (c1  >> 2)) * K + (c1  & 3) * 8;
    unsigned short* ldsA0 = ldsA + tid * 8;
    unsigned short* ldsA1 = ldsA + c1 * 8;
    unsigned short* ldsB0 = ldsB + tid * 8;
    unsigned short* ldsB1 = ldsB + c1 * 8;

    const int aReadOff = (wm * 64 + r) * 32 + quad * 8;
    const int bReadOff = (wn * 64 + r) * 32 + quad * 8;

    const int nSteps = (kEnd - kBeg) >> 5;

    async_copy16(A + aOff0 + kBeg, ldsA0);
    async_copy16(A + aOff1 + kBeg, ldsA1);
    async_copy16(B + bOff0 + kBeg, ldsB0);
    async_copy16(B + bOff1 + kBeg, ldsB1);

    for (int s = 0; s < nSteps; ++s) {
        const int cur = (s & 1) << 12;          // 0 or 4096 elems
        const int nxt = cur ^ 4096;
        __builtin_amdgcn_s_waitcnt(0);          // tile s arrived
        __syncthreads();                        // visible to all; buf[nxt] free
        if (s + 1 < nSteps) {
            const int kn = kBeg + ((s + 1) << 5);
            async_copy16(A + aOff0 + kn, ldsA0 + nxt);
            async_copy16(A + aOff1 + kn, ldsA1 + nxt);
            async_copy16(B + bOff0 + kn, ldsB0 + nxt);
            async_copy16(B + bOff1 + kn, ldsB1 + nxt);
        }
        bf16x8 af[4], bfr[4];
#pragma unroll
        for (int i = 0; i < 4; ++i)
            af[i] = *(const bf16x8*)(ldsA + cur + aReadOff + i * 16 * 32);
#pragma unroll
        for (int j = 0; j < 4; ++j)
            bfr[j] = *(const bf16x8*)(ldsB + cur + bReadOff + j * 16 * 32);
#pragma unroll
        for (int i = 0; i < 4; ++i)
#pragma unroll
            for (int j = 0; j < 4; ++j)
                acc[i][j] = __builtin_amdgcn_mfma_f32_16x16x32_bf16(af[i], bfr[j], acc[i][j], 0, 0, 0);
    }
}

// ---------- batched projections: 768 blocks (3 problems x 256), K=1024 (R7) ----------
__global__ __launch_bounds__(256, 2)
void proj_batched(const unsigned short* __restrict__ xb, const unsigned short* __restrict__ yb,
                  const unsigned short* __restrict__ wqb, const unsigned short* __restrict__ wkb,
                  const unsigned short* __restrict__ wvb,
                  unsigned short* __restrict__ q, unsigned short* __restrict__ k,
                  unsigned short* __restrict__ vt,
                  const float* __restrict__ bq, const float* __restrict__ bk,
                  const float* __restrict__ bv)
{
    __shared__ __align__(16) unsigned short ldsA[2 * 128 * 32];
    __shared__ __align__(16) unsigned short ldsB[2 * 128 * 32];

    const int b = blockIdx.x;
    const int z = b >> 8;
    const int rb = b & 255;

    const unsigned short *A, *B;
    unsigned short* C;
    const float* bias;
    int N, rowBase, colBase;
    bool biasPerRow;
    if (z == 0) {
        A = xb; B = wqb; C = q; bias = bq; N = 1024; biasPerRow = false;
        colBase = (rb >> 5) * 128; rowBase = (rb & 31) * 128;   // bid%8 = rowTile%8
    } else if (z == 1) {
        A = yb; B = wkb; C = k; bias = bk; N = 1024; biasPerRow = false;
        colBase = (rb >> 5) * 128; rowBase = (rb & 31) * 128;
    } else {
        A = wvb; B = yb; C = vt; bias = bv; N = 4096; biasPerRow = true;
        colBase = (rb >> 3) * 128; rowBase = (rb & 7) * 128;    // bid%8 = rowTile
    }

    f32x4 acc[4][4];
#pragma unroll
    for (int i = 0; i < 4; ++i)
#pragma unroll
        for (int j = 0; j < 4; ++j)
            acc[i][j] = (f32x4){0.f, 0.f, 0.f, 0.f};

    gemm_core_pf(A, B, 1024, rowBase, colBase, 0, 1024, ldsA, ldsB, acc);

    const int lane = threadIdx.x & 63;
    const int wave = threadIdx.x >> 6;
    const int quad = lane >> 4;
    const int r    = lane & 15;
    const int orow0 = rowBase + (wave >> 1) * 64 + quad * 4;
    const int ocol0 = colBase + (wave & 1) * 64 + r;

#pragma unroll
    for (int i = 0; i < 4; ++i)
#pragma unroll
        for (int e = 0; e < 4; ++e) {
            const int row = orow0 + i * 16 + e;
            const float brow = biasPerRow ? bias[row] : 0.f;
#pragma unroll
            for (int j = 0; j < 4; ++j) {
                const int col = ocol0 + j * 16;
                const float bb = biasPerRow ? brow : bias[col];
                C[(long)row * N + col] = f32_to_bf16(acc[i][j][e] + bb);
            }
        }
}

// ================= 256x256 / BK=64 / 8-wave 4-phase counted-vmcnt core =================
// m201-family structure (T2 swizzle + T3/T4 counted vmcnt + T5 setprio), phase order
// rearranged so kk0/kk1 fragment sets are never co-resident (peak frag regs 48 not 96):
//   LDS: 2 buffers x (A 32KB + B 32KB) = 128 KB. Row R of a 256-row tile at elems R*64
//   within its region; 16B chunks XOR-swizzled via the GLOBAL source address
//   (chunk ^= row&7), LDS dest linear (rule 21); ds_read applies the same involution.
//   Per K-tile (BK=64), 4 phases:
//     p1: stage B-h0(T+1)->nxt | ds_read kk0 | bar | lgkm0 | MFMA kk0 x mh0
//     p2: stage B-h1(T+1)->nxt | MFMA kk0 x mh1 (register-only)
//     p3: ds_read kk1 | bar | lgkm0 | MFMA kk1 x mh0   (kk0 frags dead after p2)
//     p4: stage A(T+2) both halves->cur | MFMA kk1 x mh1
//         (cur A reads all drained at p3's lgkm0; p3 end-barrier orders across waves)
//   Boundary: vmcnt(4) keeps only the 4 newest loads (= A(T+2)); everything older
//   (B(T+1) from p1/p2, A(T+1) from tile T-1's p4) retired -> tile T+1 fully in LDS.
//   Raw s_barrier + sched_barrier(0); vmcnt never drained to 0 in steady state.
__device__ __forceinline__ void stage_half(const unsigned short* src, long rstep,
                                           unsigned short* ldsLane) {
    async_copy16(src, ldsLane);                 // rows row0 .. row0+63
    async_copy16(src + rstep, ldsLane + 4096);  // rows row0+64 .. row0+127
}

__device__ __forceinline__ void gemm256_core(
    const unsigned short* __restrict__ A, const unsigned short* __restrict__ B,
    int K, int rowBase, int colBase, int kBeg, int nTiles,
    unsigned short* lds, f32x4 acc[8][4])
{
    const int tid  = threadIdx.x;
    const int lane = tid & 63;
    const int wid  = tid >> 6;
    const int quad = lane >> 4;
    const int r    = lane & 15;
    const int wm   = wid >> 2;     // 0..1
    const int wn   = wid & 3;      // 0..3

    // ---- staging addresses (per-thread constant) ----
    const int row0 = tid >> 3;                          // 0..63 (half covers 128 rows: +64 via rstep)
    const int chs8 = (((tid & 7) ^ (row0 & 7)) << 3);   // swizzled chunk * 8 elems
    const unsigned short* As = A + (long)(rowBase + row0) * K + chs8 + kBeg;
    const unsigned short* Bs = B + (long)(colBase + row0) * K + chs8 + kBeg;
    const long rstep = (long)K * 64;
    const long hstep = (long)K * 128;
    unsigned short* ldsLane = lds + tid * 8;

    // ---- fragment read offsets (elements) ----
    const int aRd = (wm << 13) + (r << 6);              // A region: row wm*128 + i*16 + r
    const int bRd = 16384 + (wn << 12) + (r << 6);      // B region: row wn*64  + j*16 + r
    const int sw0 = ((quad ^ (r & 7)) << 3);            // kk=0 swizzled chunk*8
    const int sw1 = (((quad + 4) ^ (r & 7)) << 3);      // kk=1

    // ---- prologue: T0 all 4 halves -> buf0; T1 A halves -> buf1 ----
    stage_half(As,         rstep, ldsLane);
    stage_half(As + hstep, rstep, ldsLane + 8192);
    stage_half(Bs,         rstep, ldsLane + 16384);
    stage_half(Bs + hstep, rstep, ldsLane + 24576);
    if (nTiles > 1) {
        stage_half(As + 64,         rstep, ldsLane + 32768);
        stage_half(As + hstep + 64, rstep, ldsLane + 40960);
    }
    __builtin_amdgcn_s_waitcnt(WAITCNT_VM(4));   // T0 arrived; T1 A halves may remain in flight
    __builtin_amdgcn_s_barrier();
    __builtin_amdgcn_sched_barrier(0);

    for (int T = 0; T < nTiles; ++T) {
        const int cur = (T & 1) << 15;   // elems
        const int nxt = cur ^ 32768;

        // ---------- phase 1: stage B-h0(T+1) -> nxt; ds_read kk0; MFMA kk0 x mh0 ----------
        bf16x8 a0[8], b0[4];
        if (T + 1 < nTiles) stage_half(Bs + (T + 1) * 64, rstep, ldsLane + nxt + 16384);
#pragma unroll
        for (int i = 0; i < 8; ++i)
            a0[i] = *(const bf16x8*)(lds + cur + aRd + i * 1024 + sw0);
#pragma unroll
        for (int j = 0; j < 4; ++j)
            b0[j] = *(const bf16x8*)(lds + cur + bRd + j * 1024 + sw0);
        __builtin_amdgcn_s_barrier();
        __builtin_amdgcn_s_waitcnt(WAITCNT_LGKM0);
        __builtin_amdgcn_sched_barrier(0);
        __builtin_amdgcn_s_setprio(1);
#pragma unroll
        for (int i = 0; i < 4; ++i)
#pragma unroll
            for (int j = 0; j < 4; ++j)
                acc[i][j] = __builtin_amdgcn_mfma_f32_16x16x32_bf16(a0[i], b0[j], acc[i][j], 0, 0, 0);
        __builtin_amdgcn_s_setprio(0);
        __builtin_amdgcn_s_barrier();

        // ---------- phase 2: stage B-h1(T+1) -> nxt; MFMA kk0 x mh1 (no reads) ----------
        if (T + 1 < nTiles) stage_half(Bs + hstep + (T + 1) * 64, rstep, ldsLane + nxt + 24576);
        __builtin_amdgcn_s_setprio(1);
#pragma unroll
        for (int i = 4; i < 8; ++i)
#pragma unroll
            for (int j = 0; j < 4; ++j)
                acc[i][j] = __builtin_amdgcn_mfma_f32_16x16x32_bf16(a0[i], b0[j], acc[i][j], 0, 0, 0);
        __builtin_amdgcn_s_setprio(0);
        __builtin_amdgcn_s_barrier();

        // ---------- phase 3: ds_read kk1; MFMA kk1 x mh0 (kk0 frags dead) ----------
        bf16x8 a1[8], b1[4];
#pragma unroll
        for (int i = 0; i < 8; ++i)
            a1[i] = *(const bf16x8*)(lds + cur + aRd + i * 1024 + sw1);
#pragma unroll
        for (int j = 0; j < 4; ++j)
            b1[j] = *(const bf16x8*)(lds + cur + bRd + j * 1024 + sw1);
        __builtin_amdgcn_s_barrier();
        __builtin_amdgcn_s_waitcnt(WAITCNT_LGKM0);   // ALL reads of cur drained here
        __builtin_amdgcn_sched_barrier(0);
        __builtin_amdgcn_s_setprio(1);
#pragma unroll
        for (int i = 0; i < 4; ++i)
#pragma unroll
            for (int j = 0; j < 4; ++j)
                acc[i][j] = __builtin_amdgcn_mfma_f32_16x16x32_bf16(a1[i], b1[j], acc[i][j], 0, 0, 0);
        __builtin_amdgcn_s_setprio(0);
        __builtin_amdgcn_s_barrier();

        // ---------- phase 4: stage A(T+2) -> cur (reads done); MFMA kk1 x mh1 ----------
        if (T + 2 < nTiles) {
            stage_half(As + (T + 2) * 64,         rstep, ldsLane + cur);
            stage_half(As + hstep + (T + 2) * 64, rstep, ldsLane + cur + 8192);
        }
        __builtin_amdgcn_s_setprio(1);
#pragma unroll
        for (int i = 4; i < 8; ++i)
#pragma unroll
            for (int j = 0; j < 4; ++j)
                acc[i][j] = __builtin_amdgcn_mfma_f32_16x16x32_bf16(a1[i], b1[j], acc[i][j], 0, 0, 0);
        __builtin_amdgcn_s_setprio(0);

        // ---------- tile boundary: T+1 must be fully in LDS ----------
        if (T + 2 < nTiles) __builtin_amdgcn_s_waitcnt(WAITCNT_VM(4)); // newest 4 = A(T+2)
        else                __builtin_amdgcn_s_waitcnt(WAITCNT_VM(0)); // tail: drain
        __builtin_amdgcn_s_barrier();
        __builtin_amdgcn_sched_barrier(0);
    }
}

// ---------- scores (256^2): P = exp2(scale2 * (q @ k^T)) bf16, lsum[row] += rowsum ----------
__global__ __launch_bounds__(512, 2)
void scores_gemm256(const unsigned short* __restrict__ q, const unsigned short* __restrict__ k,
                    unsigned short* __restrict__ P, float* __restrict__ lsum, float scale2)
{
    __shared__ __align__(16) unsigned short lds[2 * 32768];   // 128 KB

    const int bid = blockIdx.x;                    // 256 blocks
    const int swz = (bid & 7) * 32 + (bid >> 3);   // XCD-contiguous (256%8==0, bijective)
    const int mt = swz >> 4, nt = swz & 15;
    const int rowBase = mt * 256;
    const int colBase = nt * 256;

    f32x4 acc[8][4];
#pragma unroll
    for (int i = 0; i < 8; ++i)
#pragma unroll
        for (int j = 0; j < 4; ++j)
            acc[i][j] = (f32x4){0.f, 0.f, 0.f, 0.f};

    gemm256_core(q, k, 1024, rowBase, colBase, 0, 16, lds, acc);

    const int lane = threadIdx.x & 63;
    const int wid  = threadIdx.x >> 6;
    const int quad = lane >> 4;
    const int r    = lane & 15;
    const int orow0 = rowBase + (wid >> 2) * 128 + quad * 4;
    const int ocol0 = colBase + (wid & 3) * 64 + r;

#pragma unroll
    for (int mi = 0; mi < 8; ++mi)
#pragma unroll
        for (int e = 0; e < 4; ++e) {
            const int row = orow0 + mi * 16 + e;
            float rs = 0.f;
#pragma unroll
            for (int nj = 0; nj < 4; ++nj) {
                const float p = exp2f(acc[mi][nj][e] * scale2);
                rs += p;
                P[(long)row * 4096 + ocol0 + nj * 16] = f32_to_bf16(p);
            }
#pragma unroll
            for (int m = 1; m < 16; m <<= 1) rs += __shfl_xor(rs, m, 64);
            if (r == 0) atomicAdd(&lsum[row], rs);
        }
}

// ---------- output GEMM (256^2), split-K x4 ----------
// grid 256 = 16 mt x 4 nt x 4 z  -> exactly 1 block/CU, full machine.
template <int ATOMIC>
__global__ __launch_bounds__(512, 2)
void out_gemm256(const unsigned short* __restrict__ P, const unsigned short* __restrict__ vt,
                 void* __restrict__ Out)
{
    __shared__ __align__(16) unsigned short lds[2 * 32768];   // 128 KB

    const int bid = blockIdx.x;
    const int swz = (bid & 7) * 32 + (bid >> 3);
    const int z  = swz & 3;
    const int nt = (swz >> 2) & 3;
    const int mt = swz >> 4;
    const int rowBase = mt * 256;
    const int colBase = nt * 256;
    const int kBeg = z * 1024;

    f32x4 acc[8][4];
#pragma unroll
    for (int i = 0; i < 8; ++i)
#pragma unroll
        for (int j = 0; j < 4; ++j)
            acc[i][j] = (f32x4){0.f, 0.f, 0.f, 0.f};

    gemm256_core(P, vt, 4096, rowBase, colBase, kBeg, 16, lds, acc);

    const int lane = threadIdx.x & 63;
    const int wid  = threadIdx.x >> 6;
    const int quad = lane >> 4;
    const int r    = lane & 15;
    const int orow0 = rowBase + (wid >> 2) * 128 + quad * 4;
    const int ocol0 = colBase + (wid & 3) * 64 + r;

#pragma unroll
    for (int mi = 0; mi < 8; ++mi)
#pragma unroll
        for (int e = 0; e < 4; ++e) {
            const int row = orow0 + mi * 16 + e;
#pragma unroll
            for (int nj = 0; nj < 4; ++nj) {
                const int col = ocol0 + nj * 16;
                if (ATOMIC) {
                    atomicAdd(&((float*)Out)[(long)row * 1024 + col], acc[mi][nj][e]);
                } else {
                    unsigned short* parts = (unsigned short*)Out + (size_t)z * (4096 * 1024);
                    parts[(long)row * 1024 + col] = f32_to_bf16(acc[mi][nj][e]);
                }
            }
        }
}

// ---------- reduce 4 bf16 partials + normalize: O = (P0+P1+P2+P3) / lsum[row] ----------
__global__ __launch_bounds__(256) void reduce_norm4(const unsigned short* __restrict__ parts,
                                                    const float* __restrict__ lsum,
                                                    float* __restrict__ O) {
    const int i = blockIdx.x * 256 + threadIdx.x;   // ushort4 group index; 256 per row
    const float inv = 1.0f / lsum[i >> 8];
    const size_t stride = (size_t)(4096 * 1024) / 4;   // ushort4 units
    ushort4 a = ((const ushort4*)parts)[i];
    ushort4 b = ((const ushort4*)parts)[i + stride];
    ushort4 c = ((const ushort4*)parts)[i + 2 * stride];
    ushort4 d = ((const ushort4*)parts)[i + 3 * stride];
    float4 o;
    o.x = (bf16_to_f32(a.x) + bf16_to_f32(b.x) + bf16_to_f32(c.x) + bf16_to_f32(d.x)) * inv;
    o.y = (bf16_to_f32(a.y) + bf16_to_f32(b.y) + bf16_to_f32(c.y) + bf16_to_f32(d.y)) * inv;
    o.z = (bf16_to_f32(a.z) + bf16_to_f32(b.z) + bf16_to_f32(c.z) + bf16_to_f32(d.z)) * inv;
    o.w = (bf16_to_f32(a.w) + bf16_to_f32(b.w) + bf16_to_f32(c.w) + bf16_to_f32(d.w)) * inv;
    ((float4*)O)[i] = o;
}

// ---------- normalize in place (atomic fallback path) ----------
__global__ __launch_bounds__(256) void norm_rows(float* __restrict__ O, const float* __restrict__ lsum) {
    int i = blockIdx.x * 256 + threadIdx.x;
    const float inv = 1.0f / lsum[i >> 8];
    float4 v = ((const float4*)O)[i];
    v.x *= inv; v.y *= inv; v.z *= inv; v.w *= inv;
    ((float4*)O)[i] = v;
}

extern "C" void kernel_launch(void* const* d_in, const int* in_sizes, int n_in,
                              void* d_out, int out_size, void* d_ws, size_t ws_size,
                              hipStream_t stream) {
    const float* x  = (const float*)d_in[0];
    const float* y  = (const float*)d_in[1];
    const float* Wq = (const float*)d_in[2];
    const float* bq = (const float*)d_in[3];
    const float* Wk = (const float*)d_in[4];
    const float* bk = (const float*)d_in[5];
    const float* Wv = (const float*)d_in[6];
    const float* bv = (const float*)d_in[7];

    constexpr int Nx = 4096, Ny = 4096, H = 1024, Dv = 1024, Kin = 1024;

    char* ws = (char*)d_ws;
    size_t off = 0;
    auto carve = [&](size_t bytes) {
        char* p = ws + off;
        off += (bytes + 255) & ~(size_t)255;
        return p;
    };

    unsigned short* q_bf  = (unsigned short*)carve((size_t)Nx * H * 2);   // 8 MB
    unsigned short* k_bf  = (unsigned short*)carve((size_t)Ny * H * 2);   // 8 MB
    unsigned short* vt_bf = (unsigned short*)carve((size_t)Dv * Ny * 2);  // 8 MB
    float*          lsum  = (float*)carve((size_t)Nx * sizeof(float));    // 16 KB

    // overlay: phase 1 = bf16 casts (22 MB), phase 2 = P (32 MB)
    char* overlay = ws + off;
    unsigned short* x_bf  = (unsigned short*)overlay;
    unsigned short* y_bf  = x_bf  + (size_t)Nx * Kin;
    unsigned short* Wq_bf = y_bf  + (size_t)Ny * Kin;
    unsigned short* Wk_bf = Wq_bf + (size_t)H  * Kin;
    unsigned short* Wv_bf = Wk_bf + (size_t)H  * Kin;
    unsigned short* P_bf  = (unsigned short*)overlay;  // [Nx, Ny] bf16, phase 2

    // bf16 partials after the P region: 4 x 8 MB (split-K x4)
    const size_t overlay_bytes = (size_t)Nx * Ny * 2;                 // 32 MB
    const size_t partsBytes = (size_t)Nx * Dv * 2;                    // 8 MB each
    unsigned short* parts = (unsigned short*)(overlay + overlay_bytes);
    const size_t need_parts = (size_t)((overlay + overlay_bytes + 4 * partsBytes) - ws);
    const bool useParts = ws_size >= need_parts;

    if (!useParts)
        hipMemsetAsync(d_out, 0, (size_t)Nx * Dv * sizeof(float), stream);

    // phase 0: all casts + lsum zeroing, one launch
    cast_all<<<11265, 256, 0, stream>>>(x, y, Wq, Wk, Wv, x_bf, y_bf, Wq_bf, Wk_bf, Wv_bf, lsum);

    // phase 1: all three projections, one launch (768 blocks)
    proj_batched<<<768, 256, 0, stream>>>(x_bf, y_bf, Wq_bf, Wk_bf, Wv_bf,
                                          q_bf, k_bf, vt_bf, bq, bk, bv);

    // phase 2a: P = exp(q k^T / 32), lsum row sums (256 blocks x 512, 4-phase core)
    const float scale2 = 1.4426950408889634f / 32.0f;  // log2(e)/sqrt(H)
    scores_gemm256<<<256, 512, 0, stream>>>(q_bf, k_bf, P_bf, lsum, scale2);

    // phase 2b: split-K x4, 4-phase core, bf16 partials (256 blocks x 512 = 1/CU)
    if (useParts) {
        out_gemm256<0><<<256, 512, 0, stream>>>(P_bf, vt_bf, parts);
        reduce_norm4<<<(Nx * Dv / 4) / 256, 256, 0, stream>>>(parts, lsum, (float*)d_out);
    } else {
        out_gemm256<1><<<256, 512, 0, stream>>>(P_bf, vt_bf, d_out);
        norm_rows<<<Nx * Dv / 4 / 256, 256, 0, stream>>>((float*)d_out, lsum);
    }
}

// Round 3
// 223.101 us; speedup vs baseline: 1.0571x; 1.0011x over previous
//
#include <hip/hip_runtime.h>
#include <cstdint>
#include <cstddef>

// ---------- types ----------
typedef __attribute__((ext_vector_type(8))) __bf16 bf16x8;   // MFMA A/B frag (4 VGPRs)
typedef __attribute__((ext_vector_type(4))) float  f32x4;    // MFMA C/D frag

// s_waitcnt simm16 (gfx9/CDNA): [3:0] vmcnt lo, [6:4] expcnt, [11:8] lgkmcnt, [15:14] vmcnt hi
#define WAITCNT_VM(n)   ((n & 0xF) | 0x70 | 0xF00 | (((n) >> 4) << 14))  // wait vmcnt<=n only
#define WAITCNT_LGKM(n) (0xF | 0x70 | ((n) << 8) | (3 << 14))            // wait lgkmcnt<=n only

__device__ __forceinline__ unsigned short f32_to_bf16(float f) {
    union { float f; unsigned int u; } cv;
    cv.f = f;
    unsigned int u = cv.u;
    return (unsigned short)((u + 0x7fffu + ((u >> 16) & 1u)) >> 16);  // RNE
}

__device__ __forceinline__ float bf16_to_f32(unsigned short h) {
    union { unsigned int u; float f; } cv;
    cv.u = ((unsigned int)h) << 16;
    return cv.f;
}

// async global->LDS, 16 bytes per lane. LDS dest is wave-uniform base + lane*16.
__device__ __forceinline__ void async_copy16(const unsigned short* g, unsigned short* lds) {
    __builtin_amdgcn_global_load_lds(
        (const __attribute__((address_space(1))) unsigned int*)g,
        (__attribute__((address_space(3))) unsigned int*)lds,
        16, 0, 0);
}

// ---------- fused fp32 -> bf16 cast for all five inputs + lsum zeroing (R7) ----------
__global__ __launch_bounds__(256) void cast_all(
    const float* __restrict__ x,  const float* __restrict__ y,
    const float* __restrict__ wq, const float* __restrict__ wk, const float* __restrict__ wv,
    unsigned short* __restrict__ xb,  unsigned short* __restrict__ yb,
    unsigned short* __restrict__ wqb, unsigned short* __restrict__ wkb,
    unsigned short* __restrict__ wvb, float* __restrict__ lsum)
{
    int b = blockIdx.x;
    if (b >= 11264) {   // last block: zero lsum[4096]
        float4 z = {0.f, 0.f, 0.f, 0.f};
#pragma unroll
        for (int t = 0; t < 4; ++t)
            ((float4*)lsum)[threadIdx.x * 4 + t] = z;
        return;
    }
    const float* s; unsigned short* d; int base;
    if      (b < 4096)  { s = x;  d = xb;  base = b; }
    else if (b < 8192)  { s = y;  d = yb;  base = b - 4096; }
    else if (b < 9216)  { s = wq; d = wqb; base = b - 8192; }
    else if (b < 10240) { s = wk; d = wkb; base = b - 9216; }
    else                { s = wv; d = wvb; base = b - 10240; }
    int i = base * 256 + threadIdx.x;
    float4 v = ((const float4*)s)[i];
    ushort4 o;
    o.x = f32_to_bf16(v.x);
    o.y = f32_to_bf16(v.y);
    o.z = f32_to_bf16(v.z);
    o.w = f32_to_bf16(v.w);
    ((ushort4*)d)[i] = o;
}

// ---------- 1-deep prefetch GEMM core, BK=32 (R4/R7 proven; used by proj only) ----------
__device__ __forceinline__ void gemm_core_pf(
    const unsigned short* __restrict__ A, const unsigned short* __restrict__ B,
    int K, int rowBase, int colBase, int kBeg, int kEnd,
    unsigned short* ldsA, unsigned short* ldsB, f32x4 acc[4][4])
{
    const int tid  = threadIdx.x;
    const int lane = tid & 63;
    const int wave = tid >> 6;
    const int quad = lane >> 4;
    const int r    = lane & 15;
    const int wm   = wave >> 1;
    const int wn   = wave & 1;

    const int c1 = tid + 256;
    const long aOff0 = (long)(rowBase + (tid >> 2)) * K + (tid & 3) * 8;
    const long aOff1 = (long)(rowBase + (c1  >> 2)) * K + (c1  & 3) * 8;
    const long bOff0 = (long)(colBase + (tid >> 2)) * K + (tid & 3) * 8;
    const long bOff1 = (long)(colBase + (c1  >> 2)) * K + (c1  & 3) * 8;
    unsigned short* ldsA0 = ldsA + tid * 8;
    unsigned short* ldsA1 = ldsA + c1 * 8;
    unsigned short* ldsB0 = ldsB + tid * 8;
    unsigned short* ldsB1 = ldsB + c1 * 8;

    const int aReadOff = (wm * 64 + r) * 32 + quad * 8;
    const int bReadOff = (wn * 64 + r) * 32 + quad * 8;

    const int nSteps = (kEnd - kBeg) >> 5;

    async_copy16(A + aOff0 + kBeg, ldsA0);
    async_copy16(A + aOff1 + kBeg, ldsA1);
    async_copy16(B + bOff0 + kBeg, ldsB0);
    async_copy16(B + bOff1 + kBeg, ldsB1);

    for (int s = 0; s < nSteps; ++s) {
        const int cur = (s & 1) << 12;          // 0 or 4096 elems
        const int nxt = cur ^ 4096;
        __builtin_amdgcn_s_waitcnt(0);          // tile s arrived
        __syncthreads();                        // visible to all; buf[nxt] free
        if (s + 1 < nSteps) {
            const int kn = kBeg + ((s + 1) << 5);
            async_copy16(A + aOff0 + kn, ldsA0 + nxt);
            async_copy16(A + aOff1 + kn, ldsA1 + nxt);
            async_copy16(B + bOff0 + kn, ldsB0 + nxt);
            async_copy16(B + bOff1 + kn, ldsB1 + nxt);
        }
        bf16x8 af[4], bfr[4];
#pragma unroll
        for (int i = 0; i < 4; ++i)
            af[i] = *(const bf16x8*)(ldsA + cur + aReadOff + i * 16 * 32);
#pragma unroll
        for (int j = 0; j < 4; ++j)
            bfr[j] = *(const bf16x8*)(ldsB + cur + bReadOff + j * 16 * 32);
#pragma unroll
        for (int i = 0; i < 4; ++i)
#pragma unroll
            for (int j = 0; j < 4; ++j)
                acc[i][j] = __builtin_amdgcn_mfma_f32_16x16x32_bf16(af[i], bfr[j], acc[i][j], 0, 0, 0);
    }
}

// ---------- batched projections: 768 blocks (3 problems x 256), K=1024 (R7) ----------
__global__ __launch_bounds__(256, 2)
void proj_batched(const unsigned short* __restrict__ xb, const unsigned short* __restrict__ yb,
                  const unsigned short* __restrict__ wqb, const unsigned short* __restrict__ wkb,
                  const unsigned short* __restrict__ wvb,
                  unsigned short* __restrict__ q, unsigned short* __restrict__ k,
                  unsigned short* __restrict__ vt,
                  const float* __restrict__ bq, const float* __restrict__ bk,
                  const float* __restrict__ bv)
{
    __shared__ __align__(16) unsigned short ldsA[2 * 128 * 32];
    __shared__ __align__(16) unsigned short ldsB[2 * 128 * 32];

    const int b = blockIdx.x;
    const int z = b >> 8;
    const int rb = b & 255;

    const unsigned short *A, *B;
    unsigned short* C;
    const float* bias;
    int N, rowBase, colBase;
    bool biasPerRow;
    if (z == 0) {
        A = xb; B = wqb; C = q; bias = bq; N = 1024; biasPerRow = false;
        colBase = (rb >> 5) * 128; rowBase = (rb & 31) * 128;   // bid%8 = rowTile%8
    } else if (z == 1) {
        A = yb; B = wkb; C = k; bias = bk; N = 1024; biasPerRow = false;
        colBase = (rb >> 5) * 128; rowBase = (rb & 31) * 128;
    } else {
        A = wvb; B = yb; C = vt; bias = bv; N = 4096; biasPerRow = true;
        colBase = (rb >> 3) * 128; rowBase = (rb & 7) * 128;    // bid%8 = rowTile
    }

    f32x4 acc[4][4];
#pragma unroll
    for (int i = 0; i < 4; ++i)
#pragma unroll
        for (int j = 0; j < 4; ++j)
            acc[i][j] = (f32x4){0.f, 0.f, 0.f, 0.f};

    gemm_core_pf(A, B, 1024, rowBase, colBase, 0, 1024, ldsA, ldsB, acc);

    const int lane = threadIdx.x & 63;
    const int wave = threadIdx.x >> 6;
    const int quad = lane >> 4;
    const int r    = lane & 15;
    const int orow0 = rowBase + (wave >> 1) * 64 + quad * 4;
    const int ocol0 = colBase + (wave & 1) * 64 + r;

#pragma unroll
    for (int i = 0; i < 4; ++i)
#pragma unroll
        for (int e = 0; e < 4; ++e) {
            const int row = orow0 + i * 16 + e;
            const float brow = biasPerRow ? bias[row] : 0.f;
#pragma unroll
            for (int j = 0; j < 4; ++j) {
                const int col = ocol0 + j * 16;
                const float bb = biasPerRow ? brow : bias[col];
                C[(long)row * N + col] = f32_to_bf16(acc[i][j][e] + bb);
            }
        }
}

// ========== 256x256 / BK=64 / 8-wave core: one-phase-lookahead + counted lgkm ==========
// R2 post-mortem: the 4-phase core drained lgkmcnt(0) in the same phase its 12 ds_reads
// were issued -> LDS pipe and MFMA pipe strictly alternated (MfmaUtil 27%). Fix: each
// phase issues only the NEXT phase's frag reads (4 or 8 b128) and waits with a COUNTED
// lgkmcnt that retires only the PREVIOUS phase's reads -> read latency hides under the
// current 16-MFMA cluster (LDS-side analog of T4).
//   MFMA plan per K-tile: P0: a0h0 x b0, P1: a0h1 x b0, P2: a1h0 x b1, P3: a1h1 x b1
//   (aXhY = kkX, mi-half Y; 4 a-frags x 4 b-frags = 16 MFMA/phase).
//   Reads (feed NEXT phase): pre/P3(T-1): a0h0+b0 (8); P0: a0h1 (4); P1: a1h0+b1 (8);
//   P2: a1h1 (4). Waits: P0 lgkm(4), P1 lgkm(8), P2 lgkm(4), P3 lgkm(8).
//   Stages (2 gload_lds each) at PHASE END, after the barrier -- every target region's
//   last reads are retired by that phase's counted lgkm on all waves, and the barrier
//   publishes completion before the overwrite is issued (airtight WAR):
//     end-P0: A(T+1)h0 -> nxt    end-P1: A(T+1)h1 -> nxt
//     end-P2: B(T+2)h0 -> cur    end-P3: B(T+2)h1 -> cur
//   Boundary (before P3's reads of nxt): vmcnt(2) retires A(T+1)+B(T+1), keeps
//   B(T+2)h0 in flight; + barrier (cross-wave visibility). Never vmcnt(0) mid-loop.
//   Swizzle unchanged (R2-verified: bank conflicts = 0): pre-swizzled global source,
//   linear LDS dest, same involution on ds_read (rule 21).
__device__ __forceinline__ void stage_half(const unsigned short* src, long rstep,
                                           unsigned short* ldsLane) {
    async_copy16(src, ldsLane);                 // rows row0 .. row0+63
    async_copy16(src + rstep, ldsLane + 4096);  // rows row0+64 .. row0+127
}

__device__ __forceinline__ void gemm256_core(
    const unsigned short* __restrict__ A, const unsigned short* __restrict__ B,
    int K, int rowBase, int colBase, int kBeg, int nTiles,
    unsigned short* lds, f32x4 acc[8][4])
{
    const int tid  = threadIdx.x;
    const int lane = tid & 63;
    const int wid  = tid >> 6;
    const int quad = lane >> 4;
    const int r    = lane & 15;
    const int wm   = wid >> 2;     // 0..1
    const int wn   = wid & 3;      // 0..3

    // ---- staging addresses (per-thread constant) ----
    const int row0 = tid >> 3;                          // 0..63 (half covers 128 rows via rstep)
    const int chs8 = (((tid & 7) ^ (row0 & 7)) << 3);   // swizzled chunk * 8 elems
    const unsigned short* As = A + (long)(rowBase + row0) * K + chs8 + kBeg;
    const unsigned short* Bs = B + (long)(colBase + row0) * K + chs8 + kBeg;
    const long rstep = (long)K * 64;
    const long hstep = (long)K * 128;
    unsigned short* ldsLane = lds + tid * 8;

    // ---- fragment read offsets (elements) ----
    const int aRd = (wm << 13) + (r << 6);              // A region: row wm*128 + mi*16 + r
    const int bRd = 16384 + (wn << 12) + (r << 6);      // B region: row wn*64  + nj*16 + r
    const int sw0 = ((quad ^ (r & 7)) << 3);            // kk=0 swizzled chunk*8
    const int sw1 = (((quad + 4) ^ (r & 7)) << 3);      // kk=1

    // ---- prologue: T0 (A+B) -> buf0 (8 loads); B(T1) -> buf1 (4 loads) ----
    stage_half(As,         rstep, ldsLane);
    stage_half(As + hstep, rstep, ldsLane + 8192);
    stage_half(Bs,         rstep, ldsLane + 16384);
    stage_half(Bs + hstep, rstep, ldsLane + 24576);
    if (nTiles > 1) {
        stage_half(Bs + 64,         rstep, ldsLane + 32768 + 16384);
        stage_half(Bs + hstep + 64, rstep, ldsLane + 32768 + 24576);
    }
    __builtin_amdgcn_s_waitcnt(WAITCNT_VM(4));   // T0 landed; B(T1) stays in flight
    __builtin_amdgcn_s_barrier();
    __builtin_amdgcn_sched_barrier(0);

    bf16x8 aE[4], aO[4], bX[4], bY[4];
    // pre-read aE = a0h0(T0), bX = b0(T0)
#pragma unroll
    for (int i = 0; i < 4; ++i)
        aE[i] = *(const bf16x8*)(lds + aRd + i * 1024 + sw0);
#pragma unroll
    for (int j = 0; j < 4; ++j)
        bX[j] = *(const bf16x8*)(lds + bRd + j * 1024 + sw0);

    for (int T = 0; T < nTiles; ++T) {
        const int cur = (T & 1) << 15;   // elems
        const int nxt = cur ^ 32768;

        // ---------- P0: read aO=a0h1; MFMA aE x bX -> acc[0..3]; stage A(T+1)h0 ----------
#pragma unroll
        for (int i = 0; i < 4; ++i)
            aO[i] = *(const bf16x8*)(lds + cur + aRd + (4 + i) * 1024 + sw0);
        __builtin_amdgcn_s_waitcnt(WAITCNT_LGKM(4));   // prev-phase frags ready
        __builtin_amdgcn_sched_barrier(0);
        __builtin_amdgcn_s_setprio(1);
#pragma unroll
        for (int i = 0; i < 4; ++i)
#pragma unroll
            for (int j = 0; j < 4; ++j)
                acc[i][j] = __builtin_amdgcn_mfma_f32_16x16x32_bf16(aE[i], bX[j], acc[i][j], 0, 0, 0);
        __builtin_amdgcn_s_setprio(0);
        __builtin_amdgcn_sched_barrier(0);
        __builtin_amdgcn_s_barrier();
        if (T + 1 < nTiles) stage_half(As + (T + 1) * 64, rstep, ldsLane + nxt);

        // ---------- P1: read aE=a1h0, bY=b1; MFMA aO x bX -> acc[4..7]; stage A(T+1)h1 ----------
#pragma unroll
        for (int i = 0; i < 4; ++i)
            aE[i] = *(const bf16x8*)(lds + cur + aRd + i * 1024 + sw1);
#pragma unroll
        for (int j = 0; j < 4; ++j)
            bY[j] = *(const bf16x8*)(lds + cur + bRd + j * 1024 + sw1);
        __builtin_amdgcn_s_waitcnt(WAITCNT_LGKM(8));
        __builtin_amdgcn_sched_barrier(0);
        __builtin_amdgcn_s_setprio(1);
#pragma unroll
        for (int i = 0; i < 4; ++i)
#pragma unroll
            for (int j = 0; j < 4; ++j)
                acc[4 + i][j] = __builtin_amdgcn_mfma_f32_16x16x32_bf16(aO[i], bX[j], acc[4 + i][j], 0, 0, 0);
        __builtin_amdgcn_s_setprio(0);
        __builtin_amdgcn_sched_barrier(0);
        __builtin_amdgcn_s_barrier();
        if (T + 1 < nTiles) stage_half(As + hstep + (T + 1) * 64, rstep, ldsLane + nxt + 8192);

        // ---------- P2: read aO=a1h1; MFMA aE x bY -> acc[0..3]; stage B(T+2)h0 ----------
#pragma unroll
        for (int i = 0; i < 4; ++i)
            aO[i] = *(const bf16x8*)(lds + cur + aRd + (4 + i) * 1024 + sw1);
        __builtin_amdgcn_s_waitcnt(WAITCNT_LGKM(4));
        __builtin_amdgcn_sched_barrier(0);
        __builtin_amdgcn_s_setprio(1);
#pragma unroll
        for (int i = 0; i < 4; ++i)
#pragma unroll
            for (int j = 0; j < 4; ++j)
                acc[i][j] = __builtin_amdgcn_mfma_f32_16x16x32_bf16(aE[i], bY[j], acc[i][j], 0, 0, 0);
        __builtin_amdgcn_s_setprio(0);
        __builtin_amdgcn_sched_barrier(0);
        __builtin_amdgcn_s_barrier();
        if (T + 2 < nTiles) stage_half(Bs + (T + 2) * 64, rstep, ldsLane + cur + 16384);

        // ---------- P3: boundary; read aE=a0h0(T+1), bX=b0(T+1) from nxt;
        //             MFMA aO x bY -> acc[4..7]; stage B(T+2)h1 ----------
        if (T + 1 < nTiles) {
            if (T + 2 < nTiles) __builtin_amdgcn_s_waitcnt(WAITCNT_VM(2)); // retire A(T+1)+B(T+1)
            else                __builtin_amdgcn_s_waitcnt(WAITCNT_VM(0)); // tail: drain all
            __builtin_amdgcn_s_barrier();
            __builtin_amdgcn_sched_barrier(0);
#pragma unroll
            for (int i = 0; i < 4; ++i)
                aE[i] = *(const bf16x8*)(lds + nxt + aRd + i * 1024 + sw0);
#pragma unroll
            for (int j = 0; j < 4; ++j)
                bX[j] = *(const bf16x8*)(lds + nxt + bRd + j * 1024 + sw0);
            __builtin_amdgcn_s_waitcnt(WAITCNT_LGKM(8));
        } else {
            __builtin_amdgcn_s_waitcnt(WAITCNT_LGKM(0));   // last tile: just drain P2 reads
        }
        __builtin_amdgcn_sched_barrier(0);
        __builtin_amdgcn_s_setprio(1);
#pragma unroll
        for (int i = 0; i < 4; ++i)
#pragma unroll
            for (int j = 0; j < 4; ++j)
                acc[4 + i][j] = __builtin_amdgcn_mfma_f32_16x16x32_bf16(aO[i], bY[j], acc[4 + i][j], 0, 0, 0);
        __builtin_amdgcn_s_setprio(0);
        __builtin_amdgcn_sched_barrier(0);
        if (T + 2 < nTiles) stage_half(Bs + hstep + (T + 2) * 64, rstep, ldsLane + cur + 24576);
    }
}

// ---------- scores (256^2): P = exp2(scale2 * (q @ k^T)) bf16, lsum[row] += rowsum ----------
__global__ __launch_bounds__(512, 2)
void scores_gemm256(const unsigned short* __restrict__ q, const unsigned short* __restrict__ k,
                    unsigned short* __restrict__ P, float* __restrict__ lsum, float scale2)
{
    __shared__ __align__(16) unsigned short lds[2 * 32768];   // 128 KB

    const int bid = blockIdx.x;                    // 256 blocks
    const int swz = (bid & 7) * 32 + (bid >> 3);   // XCD-contiguous (256%8==0, bijective)
    const int mt = swz >> 4, nt = swz & 15;
    const int rowBase = mt * 256;
    const int colBase = nt * 256;

    f32x4 acc[8][4];
#pragma unroll
    for (int i = 0; i < 8; ++i)
#pragma unroll
        for (int j = 0; j < 4; ++j)
            acc[i][j] = (f32x4){0.f, 0.f, 0.f, 0.f};

    gemm256_core(q, k, 1024, rowBase, colBase, 0, 16, lds, acc);

    const int lane = threadIdx.x & 63;
    const int wid  = threadIdx.x >> 6;
    const int quad = lane >> 4;
    const int r    = lane & 15;
    const int orow0 = rowBase + (wid >> 2) * 128 + quad * 4;
    const int ocol0 = colBase + (wid & 3) * 64 + r;

#pragma unroll
    for (int mi = 0; mi < 8; ++mi)
#pragma unroll
        for (int e = 0; e < 4; ++e) {
            const int row = orow0 + mi * 16 + e;
            float rs = 0.f;
#pragma unroll
            for (int nj = 0; nj < 4; ++nj) {
                const float p = exp2f(acc[mi][nj][e] * scale2);
                rs += p;
                P[(long)row * 4096 + ocol0 + nj * 16] = f32_to_bf16(p);
            }
#pragma unroll
            for (int m = 1; m < 16; m <<= 1) rs += __shfl_xor(rs, m, 64);
            if (r == 0) atomicAdd(&lsum[row], rs);
        }
}

// ---------- output GEMM (256^2), split-K x4 ----------
// grid 256 = 16 mt x 4 nt x 4 z  -> exactly 1 block/CU, full machine.
template <int ATOMIC>
__global__ __launch_bounds__(512, 2)
void out_gemm256(const unsigned short* __restrict__ P, const unsigned short* __restrict__ vt,
                 void* __restrict__ Out)
{
    __shared__ __align__(16) unsigned short lds[2 * 32768];   // 128 KB

    const int bid = blockIdx.x;
    const int swz = (bid & 7) * 32 + (bid >> 3);
    const int z  = swz & 3;
    const int nt = (swz >> 2) & 3;
    const int mt = swz >> 4;
    const int rowBase = mt * 256;
    const int colBase = nt * 256;
    const int kBeg = z * 1024;

    f32x4 acc[8][4];
#pragma unroll
    for (int i = 0; i < 8; ++i)
#pragma unroll
        for (int j = 0; j < 4; ++j)
            acc[i][j] = (f32x4){0.f, 0.f, 0.f, 0.f};

    gemm256_core(P, vt, 4096, rowBase, colBase, kBeg, 16, lds, acc);

    const int lane = threadIdx.x & 63;
    const int wid  = threadIdx.x >> 6;
    const int quad = lane >> 4;
    const int r    = lane & 15;
    const int orow0 = rowBase + (wid >> 2) * 128 + quad * 4;
    const int ocol0 = colBase + (wid & 3) * 64 + r;

#pragma unroll
    for (int mi = 0; mi < 8; ++mi)
#pragma unroll
        for (int e = 0; e < 4; ++e) {
            const int row = orow0 + mi * 16 + e;
#pragma unroll
            for (int nj = 0; nj < 4; ++nj) {
                const int col = ocol0 + nj * 16;
                if (ATOMIC) {
                    atomicAdd(&((float*)Out)[(long)row * 1024 + col], acc[mi][nj][e]);
                } else {
                    unsigned short* parts = (unsigned short*)Out + (size_t)z * (4096 * 1024);
                    parts[(long)row * 1024 + col] = f32_to_bf16(acc[mi][nj][e]);
                }
            }
        }
}

// ---------- reduce 4 bf16 partials + normalize: O = (P0+P1+P2+P3) / lsum[row] ----------
__global__ __launch_bounds__(256) void reduce_norm4(const unsigned short* __restrict__ parts,
                                                    const float* __restrict__ lsum,
                                                    float* __restrict__ O) {
    const int i = blockIdx.x * 256 + threadIdx.x;   // ushort4 group index; 256 per row
    const float inv = 1.0f / lsum[i >> 8];
    const size_t stride = (size_t)(4096 * 1024) / 4;   // ushort4 units
    ushort4 a = ((const ushort4*)parts)[i];
    ushort4 b = ((const ushort4*)parts)[i + stride];
    ushort4 c = ((const ushort4*)parts)[i + 2 * stride];
    ushort4 d = ((const ushort4*)parts)[i + 3 * stride];
    float4 o;
    o.x = (bf16_to_f32(a.x) + bf16_to_f32(b.x) + bf16_to_f32(c.x) + bf16_to_f32(d.x)) * inv;
    o.y = (bf16_to_f32(a.y) + bf16_to_f32(b.y) + bf16_to_f32(c.y) + bf16_to_f32(d.y)) * inv;
    o.z = (bf16_to_f32(a.z) + bf16_to_f32(b.z) + bf16_to_f32(c.z) + bf16_to_f32(d.z)) * inv;
    o.w = (bf16_to_f32(a.w) + bf16_to_f32(b.w) + bf16_to_f32(c.w) + bf16_to_f32(d.w)) * inv;
    ((float4*)O)[i] = o;
}

// ---------- normalize in place (atomic fallback path) ----------
__global__ __launch_bounds__(256) void norm_rows(float* __restrict__ O, const float* __restrict__ lsum) {
    int i = blockIdx.x * 256 + threadIdx.x;
    const float inv = 1.0f / lsum[i >> 8];
    float4 v = ((const float4*)O)[i];
    v.x *= inv; v.y *= inv; v.z *= inv; v.w *= inv;
    ((float4*)O)[i] = v;
}

extern "C" void kernel_launch(void* const* d_in, const int* in_sizes, int n_in,
                              void* d_out, int out_size, void* d_ws, size_t ws_size,
                              hipStream_t stream) {
    const float* x  = (const float*)d_in[0];
    const float* y  = (const float*)d_in[1];
    const float* Wq = (const float*)d_in[2];
    const float* bq = (const float*)d_in[3];
    const float* Wk = (const float*)d_in[4];
    const float* bk = (const float*)d_in[5];
    const float* Wv = (const float*)d_in[6];
    const float* bv = (const float*)d_in[7];

    constexpr int Nx = 4096, Ny = 4096, H = 1024, Dv = 1024, Kin = 1024;

    char* ws = (char*)d_ws;
    size_t off = 0;
    auto carve = [&](size_t bytes) {
        char* p = ws + off;
        off += (bytes + 255) & ~(size_t)255;
        return p;
    };

    unsigned short* q_bf  = (unsigned short*)carve((size_t)Nx * H * 2);   // 8 MB
    unsigned short* k_bf  = (unsigned short*)carve((size_t)Ny * H * 2);   // 8 MB
    unsigned short* vt_bf = (unsigned short*)carve((size_t)Dv * Ny * 2);  // 8 MB
    float*          lsum  = (float*)carve((size_t)Nx * sizeof(float));    // 16 KB

    // overlay: phase 1 = bf16 casts (22 MB), phase 2 = P (32 MB)
    char* overlay = ws + off;
    unsigned short* x_bf  = (unsigned short*)overlay;
    unsigned short* y_bf  = x_bf  + (size_t)Nx * Kin;
    unsigned short* Wq_bf = y_bf  + (size_t)Ny * Kin;
    unsigned short* Wk_bf = Wq_bf + (size_t)H  * Kin;
    unsigned short* Wv_bf = Wk_bf + (size_t)H  * Kin;
    unsigned short* P_bf  = (unsigned short*)overlay;  // [Nx, Ny] bf16, phase 2

    // bf16 partials after the P region: 4 x 8 MB (split-K x4)
    const size_t overlay_bytes = (size_t)Nx * Ny * 2;                 // 32 MB
    const size_t partsBytes = (size_t)Nx * Dv * 2;                    // 8 MB each
    unsigned short* parts = (unsigned short*)(overlay + overlay_bytes);
    const size_t need_parts = (size_t)((overlay + overlay_bytes + 4 * partsBytes) - ws);
    const bool useParts = ws_size >= need_parts;

    if (!useParts)
        hipMemsetAsync(d_out, 0, (size_t)Nx * Dv * sizeof(float), stream);

    // phase 0: all casts + lsum zeroing, one launch
    cast_all<<<11265, 256, 0, stream>>>(x, y, Wq, Wk, Wv, x_bf, y_bf, Wq_bf, Wk_bf, Wv_bf, lsum);

    // phase 1: all three projections, one launch (768 blocks)
    proj_batched<<<768, 256, 0, stream>>>(x_bf, y_bf, Wq_bf, Wk_bf, Wv_bf,
                                          q_bf, k_bf, vt_bf, bq, bk, bv);

    // phase 2a: P = exp(q k^T / 32), lsum row sums (256 blocks x 512, lookahead core)
    const float scale2 = 1.4426950408889634f / 32.0f;  // log2(e)/sqrt(H)
    scores_gemm256<<<256, 512, 0, stream>>>(q_bf, k_bf, P_bf, lsum, scale2);

    // phase 2b: split-K x4, lookahead core, bf16 partials (256 blocks x 512 = 1/CU)
    if (useParts) {
        out_gemm256<0><<<256, 512, 0, stream>>>(P_bf, vt_bf, parts);
        reduce_norm4<<<(Nx * Dv / 4) / 256, 256, 0, stream>>>(parts, lsum, (float*)d_out);
    } else {
        out_gemm256<1><<<256, 512, 0, stream>>>(P_bf, vt_bf, d_out);
        norm_rows<<<Nx * Dv / 4 / 256, 256, 0, stream>>>((float*)d_out, lsum);
    }
}